// Round 13
// baseline (351.800 us; speedup 1.0000x reference)
//
#include <hip/hip_runtime.h>
#include <math.h>

#define SQ 192      // S
#define BB 192      // B
#define DM 512
#define NH 8
#define DH 64
#define NEPS 1e-5f
// log2(e)/8 — folded into aw/ar so softmax is p = 2^score via raw v_exp_f32
#define SCL 0.1803368801111204f

typedef __bf16 bf16x8 __attribute__((ext_vector_type(8)));
typedef float f32x4 __attribute__((ext_vector_type(4)));
typedef unsigned short u16x8 __attribute__((ext_vector_type(8)));
typedef unsigned short u16x4 __attribute__((ext_vector_type(4)));

__device__ __forceinline__ void gload16(const unsigned short* g, unsigned short* l) {
  __builtin_amdgcn_global_load_lds(
      (const __attribute__((address_space(1))) void*)g,
      (__attribute__((address_space(3))) void*)l, 16, 0, 0);
}
__device__ __forceinline__ unsigned short f2b(float x) {   // fp32 -> bf16 bits (RNE)
  union { float f; unsigned u; } c; c.f = x;
  return (unsigned short)((c.u + 0x7fffu + ((c.u >> 16) & 1u)) >> 16);
}
__device__ __forceinline__ float f2bf(float x) {           // round-to-bf16, keep fp32
  union { float f; unsigned u; } c; c.f = x;
  c.u = (c.u + 0x7fffu + ((c.u >> 16) & 1u)) & 0xffff0000u;
  return c.f;
}
__device__ __forceinline__ float b2f(unsigned short h) {
  union { unsigned u; float f; } c; c.u = ((unsigned)h) << 16;
  return c.f;
}
__device__ __forceinline__ bf16x8 u2b8(u16x8 v) {
  union { u16x8 u; bf16x8 b; } c; c.u = v; return c.b;
}
__device__ __forceinline__ float hexp2(float x) {          // raw v_exp_f32: 2^x
  float r;
  asm("v_exp_f32 %0, %1" : "=v"(r) : "v"(x));
  return r;
}

// ---------------------------------------------------------------------------
// Mega-launch: LN blocks [0, 36864) -> bf16 h' (b-major) in d_out;
// weight-conv tail [36864, 40960); rhk tail [40960, 41344) -> rhkb.
// ---------------------------------------------------------------------------
__global__ __launch_bounds__(128) void ln2_kernel(
    const float* __restrict__ inp, const float* __restrict__ g1, const float* __restrict__ b1,
    const float* __restrict__ g2, const float* __restrict__ b2,
    unsigned short* __restrict__ hbhi,
    const float* __restrict__ Wq, const float* __restrict__ Wo,
    unsigned short* __restrict__ wqb, unsigned short* __restrict__ wob,
    const float* __restrict__ Wr, unsigned short* __restrict__ rhkb) {
  __shared__ float red[2][2];
  __shared__ __align__(16) float pr[DM];
  if (blockIdx.x >= SQ * BB + 4096) {    // rhk tail: one (j, e-half) per block
    const int jb = blockIdx.x - (SQ * BB + 4096);
    const int j = jb >> 1;
    const int eh = (jb & 1) << 8;
    const float ps = inp[(size_t)j * DM];   // pos_seq[j] = inputs[0][j][0]
    for (int d = threadIdx.x; d < DM; d += 128) {
      const int i = d & 255;
      const float a = ps * exp2f(-0.051905126482615044f * (float)i);  // 10000^{-i/256}
      pr[d] = (d < 256) ? sinf(a) : cosf(a);
    }
    __syncthreads();
    const float4* p4 = reinterpret_cast<const float4*>(pr);
    #pragma unroll
    for (int ee = 0; ee < 2; ++ee) {
      const int e = eh + ee * 128 + threadIdx.x;
      const float4* w4 = reinterpret_cast<const float4*>(Wr + (size_t)e * DM);
      float acc = 0.f;
      #pragma unroll 8
      for (int d4 = 0; d4 < DM / 4; ++d4) {
        const float4 a = p4[d4];
        const float4 w = w4[d4];
        acc += a.x*w.x + a.y*w.y + a.z*w.z + a.w*w.w;
      }
      rhkb[(size_t)j * DM + e] = f2b(acc);
    }
    return;
  }
  if (blockIdx.x >= SQ * BB) {           // weight-conversion tail
    const int base = ((blockIdx.x - SQ * BB) * 128 + threadIdx.x) * 2;
    #pragma unroll
    for (int e = 0; e < 2; ++e) {
      const int idx = base + e;
      if (idx < 786432) wqb[idx] = f2b(Wq[idx]);
      else wob[idx - 786432] = f2b(Wo[idx - 786432]);
    }
    return;
  }
  const int R = blockIdx.x;              // input row s*B+b
  const int s = R / BB;
  const int b = R % BB;
  const int t = threadIdx.x;
  const float4 v = reinterpret_cast<const float4*>(inp + (size_t)R * DM)[t];
  float sum  = v.x + v.y + v.z + v.w;
  float sum2 = v.x*v.x + v.y*v.y + v.z*v.z + v.w*v.w;
  #pragma unroll
  for (int o = 32; o >= 1; o >>= 1) { sum += __shfl_xor(sum, o); sum2 += __shfl_xor(sum2, o); }
  const int wv = t >> 6;
  if ((t & 63) == 0) { red[0][wv] = sum; red[1][wv] = sum2; }
  __syncthreads();
  sum = red[0][0] + red[0][1]; sum2 = red[1][0] + red[1][1];
  float mu = sum * (1.0f / DM);
  float var = sum2 * (1.0f / DM) - mu * mu;
  float rstd = rsqrtf(var + NEPS);
  const float4 G1 = reinterpret_cast<const float4*>(g1)[t];
  const float4 B1 = reinterpret_cast<const float4*>(b1)[t];
  float4 x;
  x.x = (v.x - mu) * rstd * G1.x + B1.x;
  x.y = (v.y - mu) * rstd * G1.y + B1.y;
  x.z = (v.z - mu) * rstd * G1.z + B1.z;
  x.w = (v.w - mu) * rstd * G1.w + B1.w;
  sum  = x.x + x.y + x.z + x.w;
  sum2 = x.x*x.x + x.y*x.y + x.z*x.z + x.w*x.w;
  #pragma unroll
  for (int o = 32; o >= 1; o >>= 1) { sum += __shfl_xor(sum, o); sum2 += __shfl_xor(sum2, o); }
  __syncthreads();
  if ((t & 63) == 0) { red[0][wv] = sum; red[1][wv] = sum2; }
  __syncthreads();
  sum = red[0][0] + red[0][1]; sum2 = red[1][0] + red[1][1];
  mu = sum * (1.0f / DM);
  var = sum2 * (1.0f / DM) - mu * mu;
  rstd = rsqrtf(var + NEPS);
  const float4 G2 = reinterpret_cast<const float4*>(g2)[t];
  const float4 B2 = reinterpret_cast<const float4*>(b2)[t];
  ushort4 hh;
  hh.x = f2b((x.x - mu) * rstd * G2.x + B2.x);
  hh.y = f2b((x.y - mu) * rstd * G2.y + B2.y);
  hh.z = f2b((x.z - mu) * rstd * G2.z + B2.z);
  hh.w = f2b((x.w - mu) * rstd * G2.w + B2.w);
  *reinterpret_cast<ushort4*>(hbhi + ((size_t)b * SQ + s) * DM + t * 4) = hh;
}

// ---------------------------------------------------------------------------
// bf16 NT MFMA GEMM. ksteps=8: C = Ahi.Bp^T (K=512). ksteps=16: K'=1024
// split [Ahi|Alo].[Bhi|Bhi]. 128x128 tile, BK=64, 256 thr, dbuf LDS,
// XOR-swizzled source. mode 0: C -> bf16 Chi[.][1536]; mode 1: fp32 permuted.
// ---------------------------------------------------------------------------
__global__ __launch_bounds__(256, 2) void gemm_mfma(
    const unsigned short* __restrict__ Ahi, const unsigned short* __restrict__ Alo,
    const unsigned short* __restrict__ Bp,
    unsigned short* __restrict__ Chi, float* __restrict__ Cf, int N, int mode, int ksteps) {
  __shared__ __align__(16) unsigned short As[2][128][64];
  __shared__ __align__(16) unsigned short Bs[2][128][64];
  const int tid = threadIdx.x;
  const int nwg = gridDim.x * gridDim.y;
  int flat = blockIdx.y * gridDim.x + blockIdx.x;
  flat = (flat & 7) * (nwg >> 3) + (flat >> 3);
  const int bm = (flat / gridDim.x) * 128;
  const int bn = (flat % gridDim.x) * 128;
  const int lane = tid & 63, wv = tid >> 6;
  const int wm = (wv >> 1) << 6, wn = (wv & 1) << 6;
  const int fr = lane & 15, q4 = lane >> 4;
  const int srow_ = tid >> 3, sl = tid & 7;

  f32x4 acc[4][4];
  #pragma unroll
  for (int mt = 0; mt < 4; ++mt)
    #pragma unroll
    for (int nt = 0; nt < 4; ++nt) acc[mt][nt] = (f32x4){0.f, 0.f, 0.f, 0.f};

  auto STAGE = [&](int buf, int k0) {
    const unsigned short* Ap = (k0 < 512) ? Ahi : Alo;
    const int kk = k0 & 511;
    #pragma unroll
    for (int it = 0; it < 4; ++it) {
      const int row = it * 32 + srow_;
      const int sp = (sl ^ (row & 7)) << 3;
      gload16(Ap + (size_t)(bm + row) * 512 + kk + sp, &As[buf][row][sl << 3]);
      gload16(Bp + (size_t)(bn + row) * 512 + kk + sp, &Bs[buf][row][sl << 3]);
    }
  };

  STAGE(0, 0);
  __syncthreads();
  int buf = 0;
  for (int step = 0; step < ksteps; ++step) {
    if (step < ksteps - 1) STAGE(buf ^ 1, (step + 1) * 64);
    bf16x8 a[4][2], bb[4][2];
    #pragma unroll
    for (int mt = 0; mt < 4; ++mt)
      #pragma unroll
      for (int kc = 0; kc < 2; ++kc) {
        const int ra = wm + mt * 16 + fr;
        a[mt][kc]  = *reinterpret_cast<const bf16x8*>(&As[buf][ra][((((kc << 2) | q4) ^ (ra & 7)) << 3)]);
        const int rb = wn + mt * 16 + fr;
        bb[mt][kc] = *reinterpret_cast<const bf16x8*>(&Bs[buf][rb][((((kc << 2) | q4) ^ (rb & 7)) << 3)]);
      }
    #pragma unroll
    for (int mt = 0; mt < 4; ++mt)
      #pragma unroll
      for (int nt = 0; nt < 4; ++nt) {
        acc[mt][nt] = __builtin_amdgcn_mfma_f32_16x16x32_bf16(a[mt][0], bb[nt][0], acc[mt][nt], 0, 0, 0);
        acc[mt][nt] = __builtin_amdgcn_mfma_f32_16x16x32_bf16(a[mt][1], bb[nt][1], acc[mt][nt], 0, 0, 0);
      }
    __syncthreads();
    buf ^= 1;
  }
  // C/D layout: col = lane&15, row = (lane>>4)*4 + reg (verified m89)
  const int crow0 = bm + wm + (q4 << 2);
  const int ccol0 = bn + wn + fr;
  if (mode == 0) {
    #pragma unroll
    for (int mt = 0; mt < 4; ++mt)
      #pragma unroll
      for (int r = 0; r < 4; ++r) {
        const size_t rr = crow0 + mt * 16 + r;
        #pragma unroll
        for (int nt = 0; nt < 4; ++nt)
          Chi[rr * 1536 + ccol0 + nt * 16] = f2b(acc[mt][nt][r]);
      }
  } else {
    #pragma unroll
    for (int mt = 0; mt < 4; ++mt)
      #pragma unroll
      for (int r = 0; r < 4; ++r) {
        const int rr = crow0 + mt * 16 + r;
        const size_t orow = (size_t)(rr % SQ) * BB + (rr / SQ);
        #pragma unroll
        for (int nt = 0; nt < 4; ++nt)
          Cf[orow * N + ccol0 + nt * 16] = acc[mt][nt][r];
      }
  }
}

// ---------------------------------------------------------------------------
// MFMA attention v13: ONE block per (b,n), 768 thr = 12 waves.
// Diagonal-compacted rel-shift UD (verified v9): score (i,j) reads
// UD[(j+191)%192][i]; writer U[i][t] -> (m=(t+i)%192, col = t+i>=191 ? i : i-1),
// col<0 skipped; diag UD[m][m] zeroed (j==i+1 -> 0). Gather = 12 vector b64
// reads, branch-free. SCL=log2e/8 folded into aw/ar -> p = v_exp_f32(score).
// Max-free softmax. Repack pitch 84. 5 barriers.
// LDS (shorts): Q[0,12288) R[12288,24576) K[24576,36864) UD/P[36864,75264);
//   VT overlays [0,12800); OH/OL overlay [0,32256) after PV.
// ---------------------------------------------------------------------------
#define Q0   0
#define R0   12288
#define K0   24576
#define U0   36864
#define VT0  0
#define OH0  0
#define OL0  16128
#define UPIT 200
#define OPIT 84

__global__ __launch_bounds__(768) void attn_mfma(
    const unsigned short* __restrict__ qkvhi,  // [CB*192][1536] chunk-local
    const unsigned short* __restrict__ rhkb,   // [192][512]
    const float* __restrict__ rwb, const float* __restrict__ rrb,
    unsigned short* __restrict__ avhi, unsigned short* __restrict__ avlo, int b0) {
  __shared__ __align__(16) unsigned short lds[75264];   // 150528 B
  const int bid = blockIdx.x;
  const int n = bid & 7, bl = bid >> 3;
  const int tid = threadIdx.x;
  const int lane = tid & 63, wv = tid >> 6;
  const int fr = lane & 15, q4 = lane >> 4;
  const int wrow = (wv / 6) * 96 + (wv % 6) * 16;   // wave's 16-row q-slab
  const int i0q = wrow + (q4 << 2);                 // this lane's 4 q-rows
  const size_t rin = (size_t)bl * SQ;
  const size_t rout = (size_t)(b0 + bl) * SQ;

  // ---- stage: Q, R, K via gload16; V -> regs; zero UD diagonal ----
  #pragma unroll
  for (int it = 0; it < 2; ++it) {
    const int u = it * 768 + tid;
    const int row = u >> 3, sl = u & 7, sp = (sl ^ (row & 7)) << 3;
    gload16(qkvhi + (rin + row) * 1536 + n * 64 + sp, &lds[Q0 + (row << 6) + (sl << 3)]);
    gload16(rhkb + (size_t)row * 512 + n * 64 + sp, &lds[R0 + (row << 6) + (sl << 3)]);
    gload16(qkvhi + (rin + row) * 1536 + 512 + n * 64 + sp, &lds[K0 + (row << 6) + (sl << 3)]);
  }
  if (tid < 191) lds[U0 + tid * UPIT + tid] = 0;   // diag slots (j==i+1 -> 0)
  const int vj = tid % 192, vdg = tid / 192;        // vdg in [0,4)
  u16x8 vreg[2];
  #pragma unroll
  for (int c = 0; c < 2; ++c)
    vreg[c] = *reinterpret_cast<const u16x8*>(qkvhi + (rin + vj) * 1536 + 1024 + n * 64 + vdg * 16 + c * 8);
  __syncthreads();   // barrier A

  // ---- biased+scaled A-frags: aw = bf16((q+rwb)*SCL), ar = bf16((q+rrb)*SCL)
  bf16x8 aw[2], ar[2];
  {
    const int row_l = wrow + fr;
    #pragma unroll
    for (int kc = 0; kc < 2; ++kc) {
      const u16x8 qraw = *reinterpret_cast<const u16x8*>(
          &lds[Q0 + (row_l << 6) + ((((kc << 2) | q4) ^ (row_l & 7)) << 3)]);
      u16x8 wv_, rv_;
      #pragma unroll
      for (int e = 0; e < 8; ++e) {
        const int k = kc * 32 + (q4 << 3) + e;
        const float qf = b2f(qraw[e]);
        wv_[e] = f2b((qf + rwb[n * 64 + k]) * SCL);
        rv_[e] = f2b((qf + rrb[n * 64 + k]) * SCL);
      }
      aw[kc] = u2b8(wv_); ar[kc] = u2b8(rv_);
    }
  }

  // ---- AC = (q+rwb).K^T*SCL ; U = (q+rrb).R^T*SCL ----
  f32x4 acc[12], uacc[12];
  #pragma unroll
  for (int nt = 0; nt < 12; ++nt) {
    acc[nt] = (f32x4){0.f, 0.f, 0.f, 0.f};
    uacc[nt] = (f32x4){0.f, 0.f, 0.f, 0.f};
  }
  #pragma unroll
  for (int nt = 0; nt < 12; ++nt) {
    #pragma unroll
    for (int kc = 0; kc < 2; ++kc) {
      const int r_ = nt * 16 + fr;
      const int sp = ((((kc << 2) | q4) ^ (r_ & 7)) << 3);
      const bf16x8 bk = *reinterpret_cast<const bf16x8*>(&lds[K0 + (r_ << 6) + sp]);
      const bf16x8 br = *reinterpret_cast<const bf16x8*>(&lds[R0 + (r_ << 6) + sp]);
      acc[nt]  = __builtin_amdgcn_mfma_f32_16x16x32_bf16(aw[kc], bk, acc[nt], 0, 0, 0);
      uacc[nt] = __builtin_amdgcn_mfma_f32_16x16x32_bf16(ar[kc], br, uacc[nt], 0, 0, 0);
    }
  }
  // ---- UD scatter: U[i][t] -> (m=(t+i)%192, col= t+i>=191 ? i : i-1) ----
  #pragma unroll
  for (int nt = 0; nt < 12; ++nt) {
    const int t = nt * 16 + fr;
    #pragma unroll
    for (int r = 0; r < 4; ++r) {
      const int i = i0q + r;
      const int s = t + i;
      const int col = (s >= 191) ? i : (i - 1);
      const int m = (s >= 192) ? (s - 192) : s;
      if (col >= 0) lds[U0 + m * UPIT + col] = f2b(uacc[nt][r]);
    }
  }
  __syncthreads();   // barrier B: Q/R/K reads + UD writes done

  // ---- VT write (overlays Q); branch-free gather + max-free softmax ----
  #pragma unroll
  for (int c = 0; c < 2; ++c)
    #pragma unroll
    for (int e = 0; e < 8; ++e)
      lds[VT0 + (vdg * 16 + c * 8 + e) * UPIT + vj] = vreg[c][e];

  float ls[4] = {0.f, 0.f, 0.f, 0.f};
  #pragma unroll
  for (int nt = 0; nt < 12; ++nt) {
    const int j = nt * 16 + fr;
    const int m = (j == 0) ? 191 : (j - 1);
    const u16x4 uv = *reinterpret_cast<const u16x4*>(&lds[U0 + m * UPIT + i0q]);
    #pragma unroll
    for (int r = 0; r < 4; ++r) {
      const float p = hexp2(acc[nt][r] + b2f(uv[r]));
      ls[r] += p;
      acc[nt][r] = p;
    }
  }
  float linv[4];
  #pragma unroll
  for (int r = 0; r < 4; ++r) {
    #pragma unroll
    for (int o = 1; o <= 8; o <<= 1) ls[r] += __shfl_xor(ls[r], o);
    linv[r] = __builtin_amdgcn_rcpf(ls[r]);
  }
  __syncthreads();   // barrier C: UD reads done, VT visible

  // ---- P -> UD region (own-wave rows; PV reads only own rows -> no barrier)
  #pragma unroll
  for (int nt = 0; nt < 12; ++nt)
    #pragma unroll
    for (int r = 0; r < 4; ++r)
      lds[U0 + (i0q + r) * UPIT + nt * 16 + fr] = f2b(acc[nt][r]);

  // ---- PV: out[i][d] = sum_j P[i][j] Vt[d][j] ----
  f32x4 o2[4];
  #pragma unroll
  for (int nt = 0; nt < 4; ++nt) o2[nt] = (f32x4){0.f, 0.f, 0.f, 0.f};
  #pragma unroll
  for (int kc = 0; kc < 6; ++kc) {
    const bf16x8 pa = *reinterpret_cast<const bf16x8*>(
        &lds[U0 + (wrow + fr) * UPIT + kc * 32 + (q4 << 3)]);
    #pragma unroll
    for (int nt = 0; nt < 4; ++nt) {
      const bf16x8 vb = *reinterpret_cast<const bf16x8*>(
          &lds[VT0 + (nt * 16 + fr) * UPIT + kc * 32 + (q4 << 3)]);
      o2[nt] = __builtin_amdgcn_mfma_f32_16x16x32_bf16(pa, vb, o2[nt], 0, 0, 0);
    }
  }
  __syncthreads();   // barrier D: VT/P reads done -> OH/OL may overlay

  // ---- normalize, repack in LDS (pitch 84), coalesced 16B stores ----
  #pragma unroll
  for (int nt = 0; nt < 4; ++nt)
    #pragma unroll
    for (int r = 0; r < 4; ++r) {
      const int i_l = i0q + r;
      const int d = nt * 16 + fr;
      const float v = o2[nt][r] * linv[r];
      lds[OH0 + i_l * OPIT + d] = f2b(v);
      lds[OL0 + i_l * OPIT + d] = f2b(v - f2bf(v));
    }
  __syncthreads();   // barrier E
  #pragma unroll
  for (int it = 0; it < 2; ++it) {
    const int u = it * 768 + tid;
    const int row = u >> 3, sl = u & 7;
    const size_t gbase = (rout + row) * 512 + n * 64 + sl * 8;
    *reinterpret_cast<u16x8*>(avhi + gbase) = *reinterpret_cast<const u16x8*>(&lds[OH0 + row * OPIT + sl * 8]);
    *reinterpret_cast<u16x8*>(avlo + gbase) = *reinterpret_cast<const u16x8*>(&lds[OL0 + row * OPIT + sl * 8]);
  }
}

// ---------------------------------------------------------------------------
extern "C" void kernel_launch(void* const* d_in, const int* in_sizes, int n_in,
                              void* d_out, int out_size, void* d_ws, size_t ws_size,
                              hipStream_t stream) {
  const float* inp   = (const float*)d_in[0];
  const float* ln1_g = (const float*)d_in[1];
  const float* ln1_b = (const float*)d_in[2];
  const float* ln2_g = (const float*)d_in[3];
  const float* ln2_b = (const float*)d_in[4];
  const float* Wqkv  = (const float*)d_in[5];
  const float* Wr    = (const float*)d_in[6];
  const float* Wo    = (const float*)d_in[7];
  const float* rwb   = (const float*)d_in[8];
  const float* rrb   = (const float*)d_in[9];
  float* out = (float*)d_out;

  const size_t M = (size_t)SQ * BB;   // 36864
  unsigned short* hbhi = (unsigned short*)d_out;  // parked in d_out

  const int cands[3] = {192, 96, 48};
  int CB = 48;
  for (int ci = 0; ci < 3; ++ci) {
    const int c = cands[ci];
    const size_t need = (size_t)c * SQ * 1536 * 2        // qhi chunk
                      + 2 * M * 512 * 2                  // avhi + avlo
                      + 1536 * 512 * 2 + 512 * 512 * 2   // Wqb + Wob
                      + (size_t)BB * DM * 4 + (size_t)BB * DM * 2;  // slack + rhkb
    if (need <= ws_size) { CB = c; break; }
  }

  char* p = (char*)d_ws;
  unsigned short* qhi  = (unsigned short*)p; p += (size_t)CB * SQ * 1536 * 2;
  unsigned short* avhi = (unsigned short*)p; p += M * 512 * 2;
  unsigned short* avlo = (unsigned short*)p; p += M * 512 * 2;
  unsigned short* Wqb  = (unsigned short*)p; p += (size_t)1536 * 512 * 2;
  unsigned short* Wob  = (unsigned short*)p; p += (size_t)512 * 512 * 2;
  unsigned short* rhkb = (unsigned short*)p;

  // LN (36864) + weight-conv tail (4096) + rhk tail (384), one launch
  ln2_kernel<<<SQ * BB + 4096 + 384, 128, 0, stream>>>(
      inp, ln1_g, ln1_b, ln2_g, ln2_b, hbhi, Wqkv, Wo, Wqb, Wob, Wr, rhkb);

  for (int b0 = 0; b0 < BB; b0 += CB) {
    const int Mc = CB * SQ;
    // QKV: hi-only (K=512) — outputs get bf16-rounded anyway.
    gemm_mfma<<<dim3(1536 / 128, Mc / 128), 256, 0, stream>>>(
        hbhi + (size_t)b0 * SQ * DM, hbhi + (size_t)b0 * SQ * DM, Wqb,
        qhi, nullptr, 1536, 0, 8);
    attn_mfma<<<CB * NH, 768, 0, stream>>>(qhi, rhkb, rwb, rrb, avhi, avlo, b0);
  }

  // OUT: split K'=1024 (av-lo feeds compared output directly)
  gemm_mfma<<<dim3(512 / 128, M / 128), 256, 0, stream>>>(
      avhi, avlo, Wob, nullptr, out, 512, 1, 16);
}

// Round 14
// 278.008 us; speedup vs baseline: 1.2654x; 1.2654x over previous
//
#include <hip/hip_runtime.h>
#include <math.h>

#define SQ 192      // S
#define BB 192      // B
#define DM 512
#define NH 8
#define DH 64
#define NEPS 1e-5f
// log2(e)/8 — folded into aw/ar so softmax is p = 2^score via raw v_exp_f32
#define SCL 0.1803368801111204f

typedef __bf16 bf16x8 __attribute__((ext_vector_type(8)));
typedef float f32x4 __attribute__((ext_vector_type(4)));
typedef unsigned short u16x8 __attribute__((ext_vector_type(8)));
typedef unsigned short u16x4 __attribute__((ext_vector_type(4)));

__device__ __forceinline__ void gload16(const unsigned short* g, unsigned short* l) {
  __builtin_amdgcn_global_load_lds(
      (const __attribute__((address_space(1))) void*)g,
      (__attribute__((address_space(3))) void*)l, 16, 0, 0);
}
__device__ __forceinline__ unsigned short f2b(float x) {   // fp32 -> bf16 bits (RNE)
  union { float f; unsigned u; } c; c.f = x;
  return (unsigned short)((c.u + 0x7fffu + ((c.u >> 16) & 1u)) >> 16);
}
__device__ __forceinline__ float f2bf(float x) {           // round-to-bf16, keep fp32
  union { float f; unsigned u; } c; c.f = x;
  c.u = (c.u + 0x7fffu + ((c.u >> 16) & 1u)) & 0xffff0000u;
  return c.f;
}
__device__ __forceinline__ float b2f(unsigned short h) {
  union { unsigned u; float f; } c; c.u = ((unsigned)h) << 16;
  return c.f;
}
__device__ __forceinline__ bf16x8 u2b8(u16x8 v) {
  union { u16x8 u; bf16x8 b; } c; c.u = v; return c.b;
}
__device__ __forceinline__ float hexp2(float x) {          // raw v_exp_f32: 2^x
  float r;
  asm("v_exp_f32 %0, %1" : "=v"(r) : "v"(x));
  return r;
}

// ---------------------------------------------------------------------------
// LN v14: wave-per-row, no LDS, no barriers. Block = 256 thr = 4 waves = 4
// rows; lane owns 8 contiguous floats; reductions via 6 shfl_xor in-wave.
// Blocks [9216, 10240): weight conversion tail (1024 els/block).
// ---------------------------------------------------------------------------
__global__ __launch_bounds__(256) void ln2_kernel(
    const float* __restrict__ inp, const float* __restrict__ g1, const float* __restrict__ b1,
    const float* __restrict__ g2, const float* __restrict__ b2,
    unsigned short* __restrict__ hbhi,
    const float* __restrict__ Wq, const float* __restrict__ Wo,
    unsigned short* __restrict__ wqb, unsigned short* __restrict__ wob) {
  if (blockIdx.x >= (SQ * BB) / 4) {     // weight-conversion tail
    const int base = (blockIdx.x - (SQ * BB) / 4) * 1024 + threadIdx.x;
    #pragma unroll
    for (int k = 0; k < 4; ++k) {
      const int idx = base + k * 256;
      if (idx < 786432) wqb[idx] = f2b(Wq[idx]);
      else wob[idx - 786432] = f2b(Wo[idx - 786432]);
    }
    return;
  }
  const int lane = threadIdx.x & 63;
  const int wv = threadIdx.x >> 6;
  const int R = (blockIdx.x << 2) + wv;  // input row s*B+b
  const int s = R / BB;
  const int b = R % BB;
  const float4* ip = reinterpret_cast<const float4*>(inp + (size_t)R * DM) + lane * 2;
  const float4 v0 = ip[0];
  const float4 v1 = ip[1];
  float sum  = (v0.x + v0.y) + (v0.z + v0.w) + (v1.x + v1.y) + (v1.z + v1.w);
  float sum2 = v0.x*v0.x + v0.y*v0.y + v0.z*v0.z + v0.w*v0.w
             + v1.x*v1.x + v1.y*v1.y + v1.z*v1.z + v1.w*v1.w;
  #pragma unroll
  for (int o = 32; o >= 1; o >>= 1) { sum += __shfl_xor(sum, o); sum2 += __shfl_xor(sum2, o); }
  float mu = sum * (1.0f / DM);
  float var = sum2 * (1.0f / DM) - mu * mu;
  float rstd = rsqrtf(var + NEPS);
  const float4 G10 = reinterpret_cast<const float4*>(g1)[lane * 2];
  const float4 G11 = reinterpret_cast<const float4*>(g1)[lane * 2 + 1];
  const float4 B10 = reinterpret_cast<const float4*>(b1)[lane * 2];
  const float4 B11 = reinterpret_cast<const float4*>(b1)[lane * 2 + 1];
  float x[8];
  x[0] = (v0.x - mu) * rstd * G10.x + B10.x;
  x[1] = (v0.y - mu) * rstd * G10.y + B10.y;
  x[2] = (v0.z - mu) * rstd * G10.z + B10.z;
  x[3] = (v0.w - mu) * rstd * G10.w + B10.w;
  x[4] = (v1.x - mu) * rstd * G11.x + B11.x;
  x[5] = (v1.y - mu) * rstd * G11.y + B11.y;
  x[6] = (v1.z - mu) * rstd * G11.z + B11.z;
  x[7] = (v1.w - mu) * rstd * G11.w + B11.w;
  sum = 0.f; sum2 = 0.f;
  #pragma unroll
  for (int k = 0; k < 8; ++k) { sum += x[k]; sum2 += x[k] * x[k]; }
  #pragma unroll
  for (int o = 32; o >= 1; o >>= 1) { sum += __shfl_xor(sum, o); sum2 += __shfl_xor(sum2, o); }
  mu = sum * (1.0f / DM);
  var = sum2 * (1.0f / DM) - mu * mu;
  rstd = rsqrtf(var + NEPS);
  const float4 G20 = reinterpret_cast<const float4*>(g2)[lane * 2];
  const float4 G21 = reinterpret_cast<const float4*>(g2)[lane * 2 + 1];
  const float4 B20 = reinterpret_cast<const float4*>(b2)[lane * 2];
  const float4 B21 = reinterpret_cast<const float4*>(b2)[lane * 2 + 1];
  u16x8 hh;
  hh[0] = f2b((x[0] - mu) * rstd * G20.x + B20.x);
  hh[1] = f2b((x[1] - mu) * rstd * G20.y + B20.y);
  hh[2] = f2b((x[2] - mu) * rstd * G20.z + B20.z);
  hh[3] = f2b((x[3] - mu) * rstd * G20.w + B20.w);
  hh[4] = f2b((x[4] - mu) * rstd * G21.x + B21.x);
  hh[5] = f2b((x[5] - mu) * rstd * G21.y + B21.y);
  hh[6] = f2b((x[6] - mu) * rstd * G21.z + B21.z);
  hh[7] = f2b((x[7] - mu) * rstd * G21.w + B21.w);
  *reinterpret_cast<u16x8*>(hbhi + ((size_t)b * SQ + s) * DM + lane * 8) = hh;
}

// ---------------------------------------------------------------------------
// r_head_k[j][e] = sum_d pos_emb[j][d] * W_r[e][d] -> bf16 [192][512].
// pos_emb row j regenerated in-LDS (standalone; R13's merge regressed ln2).
// ---------------------------------------------------------------------------
__global__ __launch_bounds__(256) void rhk_kernel(
    const float* __restrict__ inp, const float* __restrict__ Wr,
    unsigned short* __restrict__ rhkb) {
  __shared__ __align__(16) float pr[DM];
  const int j = blockIdx.x;
  const int e = blockIdx.y * 256 + threadIdx.x;
  const float ps = inp[(size_t)j * DM];   // pos_seq[j] = inputs[0][j][0]
  for (int d = threadIdx.x; d < DM; d += 256) {
    const int i = d & 255;
    const float a = ps * exp2f(-0.051905126482615044f * (float)i);  // 10000^{-i/256}
    pr[d] = (d < 256) ? sinf(a) : cosf(a);
  }
  __syncthreads();
  const float4* w4 = reinterpret_cast<const float4*>(Wr + (size_t)e * DM);
  const float4* p4 = reinterpret_cast<const float4*>(pr);
  float acc = 0.f;
  #pragma unroll 8
  for (int d4 = 0; d4 < DM / 4; ++d4) {
    const float4 a = p4[d4];
    const float4 w = w4[d4];
    acc += a.x*w.x + a.y*w.y + a.z*w.z + a.w*w.w;
  }
  rhkb[(size_t)j * DM + e] = f2b(acc);
}

// ---------------------------------------------------------------------------
// bf16 NT MFMA GEMM. ksteps=8: C = Ahi.Bp^T (K=512). ksteps=16: K'=1024
// split [Ahi|Alo].[Bhi|Bhi]. 128x128 tile, BK=64, 256 thr, dbuf LDS,
// XOR-swizzled source. mode 0: C -> bf16 Chi[.][1536]; mode 1: fp32 permuted.
// ---------------------------------------------------------------------------
__global__ __launch_bounds__(256, 2) void gemm_mfma(
    const unsigned short* __restrict__ Ahi, const unsigned short* __restrict__ Alo,
    const unsigned short* __restrict__ Bp,
    unsigned short* __restrict__ Chi, float* __restrict__ Cf, int N, int mode, int ksteps) {
  __shared__ __align__(16) unsigned short As[2][128][64];
  __shared__ __align__(16) unsigned short Bs[2][128][64];
  const int tid = threadIdx.x;
  const int nwg = gridDim.x * gridDim.y;
  int flat = blockIdx.y * gridDim.x + blockIdx.x;
  flat = (flat & 7) * (nwg >> 3) + (flat >> 3);
  const int bm = (flat / gridDim.x) * 128;
  const int bn = (flat % gridDim.x) * 128;
  const int lane = tid & 63, wv = tid >> 6;
  const int wm = (wv >> 1) << 6, wn = (wv & 1) << 6;
  const int fr = lane & 15, q4 = lane >> 4;
  const int srow_ = tid >> 3, sl = tid & 7;

  f32x4 acc[4][4];
  #pragma unroll
  for (int mt = 0; mt < 4; ++mt)
    #pragma unroll
    for (int nt = 0; nt < 4; ++nt) acc[mt][nt] = (f32x4){0.f, 0.f, 0.f, 0.f};

  auto STAGE = [&](int buf, int k0) {
    const unsigned short* Ap = (k0 < 512) ? Ahi : Alo;
    const int kk = k0 & 511;
    #pragma unroll
    for (int it = 0; it < 4; ++it) {
      const int row = it * 32 + srow_;
      const int sp = (sl ^ (row & 7)) << 3;
      gload16(Ap + (size_t)(bm + row) * 512 + kk + sp, &As[buf][row][sl << 3]);
      gload16(Bp + (size_t)(bn + row) * 512 + kk + sp, &Bs[buf][row][sl << 3]);
    }
  };

  STAGE(0, 0);
  __syncthreads();
  int buf = 0;
  for (int step = 0; step < ksteps; ++step) {
    if (step < ksteps - 1) STAGE(buf ^ 1, (step + 1) * 64);
    bf16x8 a[4][2], bb[4][2];
    #pragma unroll
    for (int mt = 0; mt < 4; ++mt)
      #pragma unroll
      for (int kc = 0; kc < 2; ++kc) {
        const int ra = wm + mt * 16 + fr;
        a[mt][kc]  = *reinterpret_cast<const bf16x8*>(&As[buf][ra][((((kc << 2) | q4) ^ (ra & 7)) << 3)]);
        const int rb = wn + mt * 16 + fr;
        bb[mt][kc] = *reinterpret_cast<const bf16x8*>(&Bs[buf][rb][((((kc << 2) | q4) ^ (rb & 7)) << 3)]);
      }
    #pragma unroll
    for (int mt = 0; mt < 4; ++mt)
      #pragma unroll
      for (int nt = 0; nt < 4; ++nt) {
        acc[mt][nt] = __builtin_amdgcn_mfma_f32_16x16x32_bf16(a[mt][0], bb[nt][0], acc[mt][nt], 0, 0, 0);
        acc[mt][nt] = __builtin_amdgcn_mfma_f32_16x16x32_bf16(a[mt][1], bb[nt][1], acc[mt][nt], 0, 0, 0);
      }
    __syncthreads();
    buf ^= 1;
  }
  // C/D layout: col = lane&15, row = (lane>>4)*4 + reg (verified m89)
  const int crow0 = bm + wm + (q4 << 2);
  const int ccol0 = bn + wn + fr;
  if (mode == 0) {
    #pragma unroll
    for (int mt = 0; mt < 4; ++mt)
      #pragma unroll
      for (int r = 0; r < 4; ++r) {
        const size_t rr = crow0 + mt * 16 + r;
        #pragma unroll
        for (int nt = 0; nt < 4; ++nt)
          Chi[rr * 1536 + ccol0 + nt * 16] = f2b(acc[mt][nt][r]);
      }
  } else {
    #pragma unroll
    for (int mt = 0; mt < 4; ++mt)
      #pragma unroll
      for (int r = 0; r < 4; ++r) {
        const int rr = crow0 + mt * 16 + r;
        const size_t orow = (size_t)(rr % SQ) * BB + (rr / SQ);
        #pragma unroll
        for (int nt = 0; nt < 4; ++nt)
          Cf[orow * N + ccol0 + nt * 16] = acc[mt][nt][r];
      }
  }
}

// ---------------------------------------------------------------------------
// MFMA attention v13 (unchanged from R13): ONE block per (b,n), 768 thr = 12
// waves. Diagonal-compacted rel-shift UD (verified v9): score (i,j) reads
// UD[(j+191)%192][i]; writer U[i][t] -> (m=(t+i)%192, col = t+i>=191 ? i : i-1),
// col<0 skipped; diag UD[m][m] zeroed (j==i+1 -> 0). Gather = 12 vector b64
// reads, branch-free. SCL=log2e/8 folded into aw/ar -> p = v_exp_f32(score).
// Max-free softmax. Repack pitch 84. 5 barriers.
// LDS (shorts): Q[0,12288) R[12288,24576) K[24576,36864) UD/P[36864,75264);
//   VT overlays [0,12800); OH/OL overlay [0,32256) after PV.
// ---------------------------------------------------------------------------
#define Q0   0
#define R0   12288
#define K0   24576
#define U0   36864
#define VT0  0
#define OH0  0
#define OL0  16128
#define UPIT 200
#define OPIT 84

__global__ __launch_bounds__(768) void attn_mfma(
    const unsigned short* __restrict__ qkvhi,  // [CB*192][1536] chunk-local
    const unsigned short* __restrict__ rhkb,   // [192][512]
    const float* __restrict__ rwb, const float* __restrict__ rrb,
    unsigned short* __restrict__ avhi, unsigned short* __restrict__ avlo, int b0) {
  __shared__ __align__(16) unsigned short lds[75264];   // 150528 B
  const int bid = blockIdx.x;
  const int n = bid & 7, bl = bid >> 3;
  const int tid = threadIdx.x;
  const int lane = tid & 63, wv = tid >> 6;
  const int fr = lane & 15, q4 = lane >> 4;
  const int wrow = (wv / 6) * 96 + (wv % 6) * 16;   // wave's 16-row q-slab
  const int i0q = wrow + (q4 << 2);                 // this lane's 4 q-rows
  const size_t rin = (size_t)bl * SQ;
  const size_t rout = (size_t)(b0 + bl) * SQ;

  // ---- stage: Q, R, K via gload16; V -> regs; zero UD diagonal ----
  #pragma unroll
  for (int it = 0; it < 2; ++it) {
    const int u = it * 768 + tid;
    const int row = u >> 3, sl = u & 7, sp = (sl ^ (row & 7)) << 3;
    gload16(qkvhi + (rin + row) * 1536 + n * 64 + sp, &lds[Q0 + (row << 6) + (sl << 3)]);
    gload16(rhkb + (size_t)row * 512 + n * 64 + sp, &lds[R0 + (row << 6) + (sl << 3)]);
    gload16(qkvhi + (rin + row) * 1536 + 512 + n * 64 + sp, &lds[K0 + (row << 6) + (sl << 3)]);
  }
  if (tid < 191) lds[U0 + tid * UPIT + tid] = 0;   // diag slots (j==i+1 -> 0)
  const int vj = tid % 192, vdg = tid / 192;        // vdg in [0,4)
  u16x8 vreg[2];
  #pragma unroll
  for (int c = 0; c < 2; ++c)
    vreg[c] = *reinterpret_cast<const u16x8*>(qkvhi + (rin + vj) * 1536 + 1024 + n * 64 + vdg * 16 + c * 8);
  __syncthreads();   // barrier A

  // ---- biased+scaled A-frags: aw = bf16((q+rwb)*SCL), ar = bf16((q+rrb)*SCL)
  bf16x8 aw[2], ar[2];
  {
    const int row_l = wrow + fr;
    #pragma unroll
    for (int kc = 0; kc < 2; ++kc) {
      const u16x8 qraw = *reinterpret_cast<const u16x8*>(
          &lds[Q0 + (row_l << 6) + ((((kc << 2) | q4) ^ (row_l & 7)) << 3)]);
      u16x8 wv_, rv_;
      #pragma unroll
      for (int e = 0; e < 8; ++e) {
        const int k = kc * 32 + (q4 << 3) + e;
        const float qf = b2f(qraw[e]);
        wv_[e] = f2b((qf + rwb[n * 64 + k]) * SCL);
        rv_[e] = f2b((qf + rrb[n * 64 + k]) * SCL);
      }
      aw[kc] = u2b8(wv_); ar[kc] = u2b8(rv_);
    }
  }

  // ---- AC = (q+rwb).K^T*SCL ; U = (q+rrb).R^T*SCL ----
  f32x4 acc[12], uacc[12];
  #pragma unroll
  for (int nt = 0; nt < 12; ++nt) {
    acc[nt] = (f32x4){0.f, 0.f, 0.f, 0.f};
    uacc[nt] = (f32x4){0.f, 0.f, 0.f, 0.f};
  }
  #pragma unroll
  for (int nt = 0; nt < 12; ++nt) {
    #pragma unroll
    for (int kc = 0; kc < 2; ++kc) {
      const int r_ = nt * 16 + fr;
      const int sp = ((((kc << 2) | q4) ^ (r_ & 7)) << 3);
      const bf16x8 bk = *reinterpret_cast<const bf16x8*>(&lds[K0 + (r_ << 6) + sp]);
      const bf16x8 br = *reinterpret_cast<const bf16x8*>(&lds[R0 + (r_ << 6) + sp]);
      acc[nt]  = __builtin_amdgcn_mfma_f32_16x16x32_bf16(aw[kc], bk, acc[nt], 0, 0, 0);
      uacc[nt] = __builtin_amdgcn_mfma_f32_16x16x32_bf16(ar[kc], br, uacc[nt], 0, 0, 0);
    }
  }
  // ---- UD scatter: U[i][t] -> (m=(t+i)%192, col= t+i>=191 ? i : i-1) ----
  #pragma unroll
  for (int nt = 0; nt < 12; ++nt) {
    const int t = nt * 16 + fr;
    #pragma unroll
    for (int r = 0; r < 4; ++r) {
      const int i = i0q + r;
      const int s = t + i;
      const int col = (s >= 191) ? i : (i - 1);
      const int m = (s >= 192) ? (s - 192) : s;
      if (col >= 0) lds[U0 + m * UPIT + col] = f2b(uacc[nt][r]);
    }
  }
  __syncthreads();   // barrier B: Q/R/K reads + UD writes done

  // ---- VT write (overlays Q); branch-free gather + max-free softmax ----
  #pragma unroll
  for (int c = 0; c < 2; ++c)
    #pragma unroll
    for (int e = 0; e < 8; ++e)
      lds[VT0 + (vdg * 16 + c * 8 + e) * UPIT + vj] = vreg[c][e];

  float ls[4] = {0.f, 0.f, 0.f, 0.f};
  #pragma unroll
  for (int nt = 0; nt < 12; ++nt) {
    const int j = nt * 16 + fr;
    const int m = (j == 0) ? 191 : (j - 1);
    const u16x4 uv = *reinterpret_cast<const u16x4*>(&lds[U0 + m * UPIT + i0q]);
    #pragma unroll
    for (int r = 0; r < 4; ++r) {
      const float p = hexp2(acc[nt][r] + b2f(uv[r]));
      ls[r] += p;
      acc[nt][r] = p;
    }
  }
  float linv[4];
  #pragma unroll
  for (int r = 0; r < 4; ++r) {
    #pragma unroll
    for (int o = 1; o <= 8; o <<= 1) ls[r] += __shfl_xor(ls[r], o);
    linv[r] = __builtin_amdgcn_rcpf(ls[r]);
  }
  __syncthreads();   // barrier C: UD reads done, VT visible

  // ---- P -> UD region (own-wave rows; PV reads only own rows -> no barrier)
  #pragma unroll
  for (int nt = 0; nt < 12; ++nt)
    #pragma unroll
    for (int r = 0; r < 4; ++r)
      lds[U0 + (i0q + r) * UPIT + nt * 16 + fr] = f2b(acc[nt][r]);

  // ---- PV: out[i][d] = sum_j P[i][j] Vt[d][j] ----
  f32x4 o2[4];
  #pragma unroll
  for (int nt = 0; nt < 4; ++nt) o2[nt] = (f32x4){0.f, 0.f, 0.f, 0.f};
  #pragma unroll
  for (int kc = 0; kc < 6; ++kc) {
    const bf16x8 pa = *reinterpret_cast<const bf16x8*>(
        &lds[U0 + (wrow + fr) * UPIT + kc * 32 + (q4 << 3)]);
    #pragma unroll
    for (int nt = 0; nt < 4; ++nt) {
      const bf16x8 vb = *reinterpret_cast<const bf16x8*>(
          &lds[VT0 + (nt * 16 + fr) * UPIT + kc * 32 + (q4 << 3)]);
      o2[nt] = __builtin_amdgcn_mfma_f32_16x16x32_bf16(pa, vb, o2[nt], 0, 0, 0);
    }
  }
  __syncthreads();   // barrier D: VT/P reads done -> OH/OL may overlay

  // ---- normalize, repack in LDS (pitch 84), coalesced 16B stores ----
  #pragma unroll
  for (int nt = 0; nt < 4; ++nt)
    #pragma unroll
    for (int r = 0; r < 4; ++r) {
      const int i_l = i0q + r;
      const int d = nt * 16 + fr;
      const float v = o2[nt][r] * linv[r];
      lds[OH0 + i_l * OPIT + d] = f2b(v);
      lds[OL0 + i_l * OPIT + d] = f2b(v - f2bf(v));
    }
  __syncthreads();   // barrier E
  #pragma unroll
  for (int it = 0; it < 2; ++it) {
    const int u = it * 768 + tid;
    const int row = u >> 3, sl = u & 7;
    const size_t gbase = (rout + row) * 512 + n * 64 + sl * 8;
    *reinterpret_cast<u16x8*>(avhi + gbase) = *reinterpret_cast<const u16x8*>(&lds[OH0 + row * OPIT + sl * 8]);
    *reinterpret_cast<u16x8*>(avlo + gbase) = *reinterpret_cast<const u16x8*>(&lds[OL0 + row * OPIT + sl * 8]);
  }
}

// ---------------------------------------------------------------------------
extern "C" void kernel_launch(void* const* d_in, const int* in_sizes, int n_in,
                              void* d_out, int out_size, void* d_ws, size_t ws_size,
                              hipStream_t stream) {
  const float* inp   = (const float*)d_in[0];
  const float* ln1_g = (const float*)d_in[1];
  const float* ln1_b = (const float*)d_in[2];
  const float* ln2_g = (const float*)d_in[3];
  const float* ln2_b = (const float*)d_in[4];
  const float* Wqkv  = (const float*)d_in[5];
  const float* Wr    = (const float*)d_in[6];
  const float* Wo    = (const float*)d_in[7];
  const float* rwb   = (const float*)d_in[8];
  const float* rrb   = (const float*)d_in[9];
  float* out = (float*)d_out;

  const size_t M = (size_t)SQ * BB;   // 36864
  unsigned short* hbhi = (unsigned short*)d_out;  // parked in d_out

  const int cands[3] = {192, 96, 48};
  int CB = 48;
  for (int ci = 0; ci < 3; ++ci) {
    const int c = cands[ci];
    const size_t need = (size_t)c * SQ * 1536 * 2        // qhi chunk
                      + 2 * M * 512 * 2                  // avhi + avlo
                      + 1536 * 512 * 2 + 512 * 512 * 2   // Wqb + Wob
                      + (size_t)BB * DM * 4 + (size_t)BB * DM * 2;  // slack + rhkb
    if (need <= ws_size) { CB = c; break; }
  }

  char* p = (char*)d_ws;
  unsigned short* qhi  = (unsigned short*)p; p += (size_t)CB * SQ * 1536 * 2;
  unsigned short* avhi = (unsigned short*)p; p += M * 512 * 2;
  unsigned short* avlo = (unsigned short*)p; p += M * 512 * 2;
  unsigned short* Wqb  = (unsigned short*)p; p += (size_t)1536 * 512 * 2;
  unsigned short* Wob  = (unsigned short*)p; p += (size_t)512 * 512 * 2;
  unsigned short* rhkb = (unsigned short*)p;

  // LN (9216 blocks, 4 rows each) + weight-conv tail (1024 blocks)
  ln2_kernel<<<(SQ * BB) / 4 + 1024, 256, 0, stream>>>(
      inp, ln1_g, ln1_b, ln2_g, ln2_b, hbhi, Wqkv, Wo, Wqb, Wob);
  rhk_kernel<<<dim3(BB, DM / 256), 256, 0, stream>>>(inp, Wr, rhkb);

  for (int b0 = 0; b0 < BB; b0 += CB) {
    const int Mc = CB * SQ;
    // QKV: hi-only (K=512) — outputs get bf16-rounded anyway.
    gemm_mfma<<<dim3(1536 / 128, Mc / 128), 256, 0, stream>>>(
        hbhi + (size_t)b0 * SQ * DM, hbhi + (size_t)b0 * SQ * DM, Wqb,
        qhi, nullptr, 1536, 0, 8);
    attn_mfma<<<CB * NH, 768, 0, stream>>>(qhi, rhkb, rwb, rrb, avhi, avlo, b0);
  }

  // OUT: split K'=1024 (av-lo feeds compared output directly)
  gemm_mfma<<<dim3(512 / 128, M / 128), 256, 0, stream>>>(
      avhi, avlo, Wob, nullptr, out, 512, 1, 16);
}

// Round 15
// 247.050 us; speedup vs baseline: 1.4240x; 1.1253x over previous
//
#include <hip/hip_runtime.h>
#include <math.h>

#define SQ 192      // S
#define BB 192      // B
#define DM 512
#define NH 8
#define DH 64
#define NEPS 1e-5f
// log2(e)/8 — folded into aw/ar so softmax is p = 2^score via raw v_exp_f32
#define SCL 0.1803368801111204f

typedef __bf16 bf16x8 __attribute__((ext_vector_type(8)));
typedef float f32x4 __attribute__((ext_vector_type(4)));
typedef unsigned short u16x8 __attribute__((ext_vector_type(8)));
typedef unsigned short u16x4 __attribute__((ext_vector_type(4)));

__device__ __forceinline__ void gload16(const unsigned short* g, unsigned short* l) {
  __builtin_amdgcn_global_load_lds(
      (const __attribute__((address_space(1))) void*)g,
      (__attribute__((address_space(3))) void*)l, 16, 0, 0);
}
__device__ __forceinline__ unsigned short f2b(float x) {   // fp32 -> bf16 bits (RNE)
  union { float f; unsigned u; } c; c.f = x;
  return (unsigned short)((c.u + 0x7fffu + ((c.u >> 16) & 1u)) >> 16);
}
__device__ __forceinline__ float f2bf(float x) {           // round-to-bf16, keep fp32
  union { float f; unsigned u; } c; c.f = x;
  c.u = (c.u + 0x7fffu + ((c.u >> 16) & 1u)) & 0xffff0000u;
  return c.f;
}
__device__ __forceinline__ float b2f(unsigned short h) {
  union { unsigned u; float f; } c; c.u = ((unsigned)h) << 16;
  return c.f;
}
__device__ __forceinline__ bf16x8 u2b8(u16x8 v) {
  union { u16x8 u; bf16x8 b; } c; c.u = v; return c.b;
}
__device__ __forceinline__ float hexp2(float x) {          // raw v_exp_f32: 2^x
  float r;
  asm("v_exp_f32 %0, %1" : "=v"(r) : "v"(x));
  return r;
}

// ---------------------------------------------------------------------------
// LN v14: wave-per-row, no LDS, no barriers. Block = 256 thr = 4 waves = 4
// rows; lane owns 8 contiguous floats; reductions via 6 shfl_xor in-wave.
// Blocks [9216, 10240): weight conversion tail (1024 els/block).
// ---------------------------------------------------------------------------
__global__ __launch_bounds__(256) void ln2_kernel(
    const float* __restrict__ inp, const float* __restrict__ g1, const float* __restrict__ b1,
    const float* __restrict__ g2, const float* __restrict__ b2,
    unsigned short* __restrict__ hbhi,
    const float* __restrict__ Wq, const float* __restrict__ Wo,
    unsigned short* __restrict__ wqb, unsigned short* __restrict__ wob) {
  if (blockIdx.x >= (SQ * BB) / 4) {     // weight-conversion tail
    const int base = (blockIdx.x - (SQ * BB) / 4) * 1024 + threadIdx.x;
    #pragma unroll
    for (int k = 0; k < 4; ++k) {
      const int idx = base + k * 256;
      if (idx < 786432) wqb[idx] = f2b(Wq[idx]);
      else wob[idx - 786432] = f2b(Wo[idx - 786432]);
    }
    return;
  }
  const int lane = threadIdx.x & 63;
  const int wv = threadIdx.x >> 6;
  const int R = (blockIdx.x << 2) + wv;  // input row s*B+b
  const int s = R / BB;
  const int b = R % BB;
  const float4* ip = reinterpret_cast<const float4*>(inp + (size_t)R * DM) + lane * 2;
  const float4 v0 = ip[0];
  const float4 v1 = ip[1];
  float sum  = (v0.x + v0.y) + (v0.z + v0.w) + (v1.x + v1.y) + (v1.z + v1.w);
  float sum2 = v0.x*v0.x + v0.y*v0.y + v0.z*v0.z + v0.w*v0.w
             + v1.x*v1.x + v1.y*v1.y + v1.z*v1.z + v1.w*v1.w;
  #pragma unroll
  for (int o = 32; o >= 1; o >>= 1) { sum += __shfl_xor(sum, o); sum2 += __shfl_xor(sum2, o); }
  float mu = sum * (1.0f / DM);
  float var = sum2 * (1.0f / DM) - mu * mu;
  float rstd = rsqrtf(var + NEPS);
  const float4 G10 = reinterpret_cast<const float4*>(g1)[lane * 2];
  const float4 G11 = reinterpret_cast<const float4*>(g1)[lane * 2 + 1];
  const float4 B10 = reinterpret_cast<const float4*>(b1)[lane * 2];
  const float4 B11 = reinterpret_cast<const float4*>(b1)[lane * 2 + 1];
  float x[8];
  x[0] = (v0.x - mu) * rstd * G10.x + B10.x;
  x[1] = (v0.y - mu) * rstd * G10.y + B10.y;
  x[2] = (v0.z - mu) * rstd * G10.z + B10.z;
  x[3] = (v0.w - mu) * rstd * G10.w + B10.w;
  x[4] = (v1.x - mu) * rstd * G11.x + B11.x;
  x[5] = (v1.y - mu) * rstd * G11.y + B11.y;
  x[6] = (v1.z - mu) * rstd * G11.z + B11.z;
  x[7] = (v1.w - mu) * rstd * G11.w + B11.w;
  sum = 0.f; sum2 = 0.f;
  #pragma unroll
  for (int k = 0; k < 8; ++k) { sum += x[k]; sum2 += x[k] * x[k]; }
  #pragma unroll
  for (int o = 32; o >= 1; o >>= 1) { sum += __shfl_xor(sum, o); sum2 += __shfl_xor(sum2, o); }
  mu = sum * (1.0f / DM);
  var = sum2 * (1.0f / DM) - mu * mu;
  rstd = rsqrtf(var + NEPS);
  const float4 G20 = reinterpret_cast<const float4*>(g2)[lane * 2];
  const float4 G21 = reinterpret_cast<const float4*>(g2)[lane * 2 + 1];
  const float4 B20 = reinterpret_cast<const float4*>(b2)[lane * 2];
  const float4 B21 = reinterpret_cast<const float4*>(b2)[lane * 2 + 1];
  u16x8 hh;
  hh[0] = f2b((x[0] - mu) * rstd * G20.x + B20.x);
  hh[1] = f2b((x[1] - mu) * rstd * G20.y + B20.y);
  hh[2] = f2b((x[2] - mu) * rstd * G20.z + B20.z);
  hh[3] = f2b((x[3] - mu) * rstd * G20.w + B20.w);
  hh[4] = f2b((x[4] - mu) * rstd * G21.x + B21.x);
  hh[5] = f2b((x[5] - mu) * rstd * G21.y + B21.y);
  hh[6] = f2b((x[6] - mu) * rstd * G21.z + B21.z);
  hh[7] = f2b((x[7] - mu) * rstd * G21.w + B21.w);
  *reinterpret_cast<u16x8*>(hbhi + ((size_t)b * SQ + s) * DM + lane * 8) = hh;
}

// ---------------------------------------------------------------------------
// r_head_k[j][e] = sum_d pos_emb[j][d] * W_r[e][d] -> bf16 [192][512].
// pos_emb row j regenerated in-LDS.
// ---------------------------------------------------------------------------
__global__ __launch_bounds__(256) void rhk_kernel(
    const float* __restrict__ inp, const float* __restrict__ Wr,
    unsigned short* __restrict__ rhkb) {
  __shared__ __align__(16) float pr[DM];
  const int j = blockIdx.x;
  const int e = blockIdx.y * 256 + threadIdx.x;
  const float ps = inp[(size_t)j * DM];   // pos_seq[j] = inputs[0][j][0]
  for (int d = threadIdx.x; d < DM; d += 256) {
    const int i = d & 255;
    const float a = ps * exp2f(-0.051905126482615044f * (float)i);  // 10000^{-i/256}
    pr[d] = (d < 256) ? sinf(a) : cosf(a);
  }
  __syncthreads();
  const float4* w4 = reinterpret_cast<const float4*>(Wr + (size_t)e * DM);
  const float4* p4 = reinterpret_cast<const float4*>(pr);
  float acc = 0.f;
  #pragma unroll 8
  for (int d4 = 0; d4 < DM / 4; ++d4) {
    const float4 a = p4[d4];
    const float4 w = w4[d4];
    acc += a.x*w.x + a.y*w.y + a.z*w.z + a.w*w.w;
  }
  rhkb[(size_t)j * DM + e] = f2b(acc);
}

// ---------------------------------------------------------------------------
// bf16 NT MFMA GEMM. ksteps=8: C = Ahi.Bp^T (K=512). ksteps=16: K'=1024
// split [Ahi|Alo].[Bhi|Bhi]. 128x128 tile, BK=64, 256 thr, dbuf LDS,
// XOR-swizzled source. mode 0: C -> bf16 Chi[.][1536]; mode 1: fp32 permuted.
// ---------------------------------------------------------------------------
__global__ __launch_bounds__(256, 2) void gemm_mfma(
    const unsigned short* __restrict__ Ahi, const unsigned short* __restrict__ Alo,
    const unsigned short* __restrict__ Bp,
    unsigned short* __restrict__ Chi, float* __restrict__ Cf, int N, int mode, int ksteps) {
  __shared__ __align__(16) unsigned short As[2][128][64];
  __shared__ __align__(16) unsigned short Bs[2][128][64];
  const int tid = threadIdx.x;
  const int nwg = gridDim.x * gridDim.y;
  int flat = blockIdx.y * gridDim.x + blockIdx.x;
  flat = (flat & 7) * (nwg >> 3) + (flat >> 3);
  const int bm = (flat / gridDim.x) * 128;
  const int bn = (flat % gridDim.x) * 128;
  const int lane = tid & 63, wv = tid >> 6;
  const int wm = (wv >> 1) << 6, wn = (wv & 1) << 6;
  const int fr = lane & 15, q4 = lane >> 4;
  const int srow_ = tid >> 3, sl = tid & 7;

  f32x4 acc[4][4];
  #pragma unroll
  for (int mt = 0; mt < 4; ++mt)
    #pragma unroll
    for (int nt = 0; nt < 4; ++nt) acc[mt][nt] = (f32x4){0.f, 0.f, 0.f, 0.f};

  auto STAGE = [&](int buf, int k0) {
    const unsigned short* Ap = (k0 < 512) ? Ahi : Alo;
    const int kk = k0 & 511;
    #pragma unroll
    for (int it = 0; it < 4; ++it) {
      const int row = it * 32 + srow_;
      const int sp = (sl ^ (row & 7)) << 3;
      gload16(Ap + (size_t)(bm + row) * 512 + kk + sp, &As[buf][row][sl << 3]);
      gload16(Bp + (size_t)(bn + row) * 512 + kk + sp, &Bs[buf][row][sl << 3]);
    }
  };

  STAGE(0, 0);
  __syncthreads();
  int buf = 0;
  for (int step = 0; step < ksteps; ++step) {
    if (step < ksteps - 1) STAGE(buf ^ 1, (step + 1) * 64);
    bf16x8 a[4][2], bb[4][2];
    #pragma unroll
    for (int mt = 0; mt < 4; ++mt)
      #pragma unroll
      for (int kc = 0; kc < 2; ++kc) {
        const int ra = wm + mt * 16 + fr;
        a[mt][kc]  = *reinterpret_cast<const bf16x8*>(&As[buf][ra][((((kc << 2) | q4) ^ (ra & 7)) << 3)]);
        const int rb = wn + mt * 16 + fr;
        bb[mt][kc] = *reinterpret_cast<const bf16x8*>(&Bs[buf][rb][((((kc << 2) | q4) ^ (rb & 7)) << 3)]);
      }
    #pragma unroll
    for (int mt = 0; mt < 4; ++mt)
      #pragma unroll
      for (int nt = 0; nt < 4; ++nt) {
        acc[mt][nt] = __builtin_amdgcn_mfma_f32_16x16x32_bf16(a[mt][0], bb[nt][0], acc[mt][nt], 0, 0, 0);
        acc[mt][nt] = __builtin_amdgcn_mfma_f32_16x16x32_bf16(a[mt][1], bb[nt][1], acc[mt][nt], 0, 0, 0);
      }
    __syncthreads();
    buf ^= 1;
  }
  // C/D layout: col = lane&15, row = (lane>>4)*4 + reg (verified m89)
  const int crow0 = bm + wm + (q4 << 2);
  const int ccol0 = bn + wn + fr;
  if (mode == 0) {
    #pragma unroll
    for (int mt = 0; mt < 4; ++mt)
      #pragma unroll
      for (int r = 0; r < 4; ++r) {
        const size_t rr = crow0 + mt * 16 + r;
        #pragma unroll
        for (int nt = 0; nt < 4; ++nt)
          Chi[rr * 1536 + ccol0 + nt * 16] = f2b(acc[mt][nt][r]);
      }
  } else {
    #pragma unroll
    for (int mt = 0; mt < 4; ++mt)
      #pragma unroll
      for (int r = 0; r < 4; ++r) {
        const int rr = crow0 + mt * 16 + r;
        const size_t orow = (size_t)(rr % SQ) * BB + (rr / SQ);
        #pragma unroll
        for (int nt = 0; nt < 4; ++nt)
          Cf[orow * N + ccol0 + nt * 16] = acc[mt][nt][r];
      }
  }
}

// ---------------------------------------------------------------------------
// MFMA attention v15: ONE block per (b,n), 768 thr = 12 waves.
// Diagonal-compacted rel-shift UD (verified v9): score (i,j) reads
// UD[(j+191)%192][i]; writer U[i][t] -> (m=(t+i)%192, col = t+i>=191 ? i : i-1),
// col<0 skipped; diag UD[m][m] zeroed (j==i+1 -> 0). Gather = 12 vector b64
// reads, branch-free. SCL=log2e/8 folded into aw/ar -> p = v_exp_f32(score).
// Max-free softmax. Repack pitch 84. av hi-only (lo plane dropped in R15).
// LDS (shorts): Q[0,12288) R[12288,24576) K[24576,36864) UD/P[36864,75264);
//   VT overlays [0,12800); OH overlays [0,16128) after PV. 5 barriers.
// ---------------------------------------------------------------------------
#define Q0   0
#define R0   12288
#define K0   24576
#define U0   36864
#define VT0  0
#define OH0  0
#define UPIT 200
#define OPIT 84

__global__ __launch_bounds__(768) void attn_mfma(
    const unsigned short* __restrict__ qkvhi,  // [CB*192][1536] chunk-local
    const unsigned short* __restrict__ rhkb,   // [192][512]
    const float* __restrict__ rwb, const float* __restrict__ rrb,
    unsigned short* __restrict__ avhi, int b0) {
  __shared__ __align__(16) unsigned short lds[75264];   // 150528 B
  const int bid = blockIdx.x;
  const int n = bid & 7, bl = bid >> 3;
  const int tid = threadIdx.x;
  const int lane = tid & 63, wv = tid >> 6;
  const int fr = lane & 15, q4 = lane >> 4;
  const int wrow = (wv / 6) * 96 + (wv % 6) * 16;   // wave's 16-row q-slab
  const int i0q = wrow + (q4 << 2);                 // this lane's 4 q-rows
  const size_t rin = (size_t)bl * SQ;
  const size_t rout = (size_t)(b0 + bl) * SQ;

  // ---- stage: Q, R, K via gload16; V -> regs; zero UD diagonal ----
  #pragma unroll
  for (int it = 0; it < 2; ++it) {
    const int u = it * 768 + tid;
    const int row = u >> 3, sl = u & 7, sp = (sl ^ (row & 7)) << 3;
    gload16(qkvhi + (rin + row) * 1536 + n * 64 + sp, &lds[Q0 + (row << 6) + (sl << 3)]);
    gload16(rhkb + (size_t)row * 512 + n * 64 + sp, &lds[R0 + (row << 6) + (sl << 3)]);
    gload16(qkvhi + (rin + row) * 1536 + 512 + n * 64 + sp, &lds[K0 + (row << 6) + (sl << 3)]);
  }
  if (tid < 191) lds[U0 + tid * UPIT + tid] = 0;   // diag slots (j==i+1 -> 0)
  const int vj = tid % 192, vdg = tid / 192;        // vdg in [0,4)
  u16x8 vreg[2];
  #pragma unroll
  for (int c = 0; c < 2; ++c)
    vreg[c] = *reinterpret_cast<const u16x8*>(qkvhi + (rin + vj) * 1536 + 1024 + n * 64 + vdg * 16 + c * 8);
  __syncthreads();   // barrier A

  // ---- biased+scaled A-frags: aw = bf16((q+rwb)*SCL), ar = bf16((q+rrb)*SCL)
  bf16x8 aw[2], ar[2];
  {
    const int row_l = wrow + fr;
    #pragma unroll
    for (int kc = 0; kc < 2; ++kc) {
      const u16x8 qraw = *reinterpret_cast<const u16x8*>(
          &lds[Q0 + (row_l << 6) + ((((kc << 2) | q4) ^ (row_l & 7)) << 3)]);
      u16x8 wv_, rv_;
      #pragma unroll
      for (int e = 0; e < 8; ++e) {
        const int k = kc * 32 + (q4 << 3) + e;
        const float qf = b2f(qraw[e]);
        wv_[e] = f2b((qf + rwb[n * 64 + k]) * SCL);
        rv_[e] = f2b((qf + rrb[n * 64 + k]) * SCL);
      }
      aw[kc] = u2b8(wv_); ar[kc] = u2b8(rv_);
    }
  }

  // ---- AC = (q+rwb).K^T*SCL ; U = (q+rrb).R^T*SCL ----
  f32x4 acc[12], uacc[12];
  #pragma unroll
  for (int nt = 0; nt < 12; ++nt) {
    acc[nt] = (f32x4){0.f, 0.f, 0.f, 0.f};
    uacc[nt] = (f32x4){0.f, 0.f, 0.f, 0.f};
  }
  #pragma unroll
  for (int nt = 0; nt < 12; ++nt) {
    #pragma unroll
    for (int kc = 0; kc < 2; ++kc) {
      const int r_ = nt * 16 + fr;
      const int sp = ((((kc << 2) | q4) ^ (r_ & 7)) << 3);
      const bf16x8 bk = *reinterpret_cast<const bf16x8*>(&lds[K0 + (r_ << 6) + sp]);
      const bf16x8 br = *reinterpret_cast<const bf16x8*>(&lds[R0 + (r_ << 6) + sp]);
      acc[nt]  = __builtin_amdgcn_mfma_f32_16x16x32_bf16(aw[kc], bk, acc[nt], 0, 0, 0);
      uacc[nt] = __builtin_amdgcn_mfma_f32_16x16x32_bf16(ar[kc], br, uacc[nt], 0, 0, 0);
    }
  }
  // ---- UD scatter: U[i][t] -> (m=(t+i)%192, col= t+i>=191 ? i : i-1) ----
  #pragma unroll
  for (int nt = 0; nt < 12; ++nt) {
    const int t = nt * 16 + fr;
    #pragma unroll
    for (int r = 0; r < 4; ++r) {
      const int i = i0q + r;
      const int s = t + i;
      const int col = (s >= 191) ? i : (i - 1);
      const int m = (s >= 192) ? (s - 192) : s;
      if (col >= 0) lds[U0 + m * UPIT + col] = f2b(uacc[nt][r]);
    }
  }
  __syncthreads();   // barrier B: Q/R/K reads + UD writes done

  // ---- VT write (overlays Q); branch-free gather + max-free softmax ----
  #pragma unroll
  for (int c = 0; c < 2; ++c)
    #pragma unroll
    for (int e = 0; e < 8; ++e)
      lds[VT0 + (vdg * 16 + c * 8 + e) * UPIT + vj] = vreg[c][e];

  float ls[4] = {0.f, 0.f, 0.f, 0.f};
  #pragma unroll
  for (int nt = 0; nt < 12; ++nt) {
    const int j = nt * 16 + fr;
    const int m = (j == 0) ? 191 : (j - 1);
    const u16x4 uv = *reinterpret_cast<const u16x4*>(&lds[U0 + m * UPIT + i0q]);
    #pragma unroll
    for (int r = 0; r < 4; ++r) {
      const float p = hexp2(acc[nt][r] + b2f(uv[r]));
      ls[r] += p;
      acc[nt][r] = p;
    }
  }
  float linv[4];
  #pragma unroll
  for (int r = 0; r < 4; ++r) {
    #pragma unroll
    for (int o = 1; o <= 8; o <<= 1) ls[r] += __shfl_xor(ls[r], o);
    linv[r] = __builtin_amdgcn_rcpf(ls[r]);
  }
  __syncthreads();   // barrier C: UD reads done, VT visible

  // ---- P -> UD region (own-wave rows; PV reads only own rows -> no barrier)
  #pragma unroll
  for (int nt = 0; nt < 12; ++nt)
    #pragma unroll
    for (int r = 0; r < 4; ++r)
      lds[U0 + (i0q + r) * UPIT + nt * 16 + fr] = f2b(acc[nt][r]);

  // ---- PV: out[i][d] = sum_j P[i][j] Vt[d][j] ----
  f32x4 o2[4];
  #pragma unroll
  for (int nt = 0; nt < 4; ++nt) o2[nt] = (f32x4){0.f, 0.f, 0.f, 0.f};
  #pragma unroll
  for (int kc = 0; kc < 6; ++kc) {
    const bf16x8 pa = *reinterpret_cast<const bf16x8*>(
        &lds[U0 + (wrow + fr) * UPIT + kc * 32 + (q4 << 3)]);
    #pragma unroll
    for (int nt = 0; nt < 4; ++nt) {
      const bf16x8 vb = *reinterpret_cast<const bf16x8*>(
          &lds[VT0 + (nt * 16 + fr) * UPIT + kc * 32 + (q4 << 3)]);
      o2[nt] = __builtin_amdgcn_mfma_f32_16x16x32_bf16(pa, vb, o2[nt], 0, 0, 0);
    }
  }
  __syncthreads();   // barrier D: VT/P reads done -> OH may overlay

  // ---- normalize, repack in LDS (pitch 84), coalesced 16B stores ----
  #pragma unroll
  for (int nt = 0; nt < 4; ++nt)
    #pragma unroll
    for (int r = 0; r < 4; ++r) {
      const int i_l = i0q + r;
      const int d = nt * 16 + fr;
      lds[OH0 + i_l * OPIT + d] = f2b(o2[nt][r] * linv[r]);
    }
  __syncthreads();   // barrier E
  #pragma unroll
  for (int it = 0; it < 2; ++it) {
    const int u = it * 768 + tid;
    const int row = u >> 3, sl = u & 7;
    const size_t gbase = (rout + row) * 512 + n * 64 + sl * 8;
    *reinterpret_cast<u16x8*>(avhi + gbase) = *reinterpret_cast<const u16x8*>(&lds[OH0 + row * OPIT + sl * 8]);
  }
}

// ---------------------------------------------------------------------------
extern "C" void kernel_launch(void* const* d_in, const int* in_sizes, int n_in,
                              void* d_out, int out_size, void* d_ws, size_t ws_size,
                              hipStream_t stream) {
  const float* inp   = (const float*)d_in[0];
  const float* ln1_g = (const float*)d_in[1];
  const float* ln1_b = (const float*)d_in[2];
  const float* ln2_g = (const float*)d_in[3];
  const float* ln2_b = (const float*)d_in[4];
  const float* Wqkv  = (const float*)d_in[5];
  const float* Wr    = (const float*)d_in[6];
  const float* Wo    = (const float*)d_in[7];
  const float* rwb   = (const float*)d_in[8];
  const float* rrb   = (const float*)d_in[9];
  float* out = (float*)d_out;

  const size_t M = (size_t)SQ * BB;   // 36864
  unsigned short* hbhi = (unsigned short*)d_out;  // parked in d_out

  const int cands[3] = {192, 96, 48};
  int CB = 48;
  for (int ci = 0; ci < 3; ++ci) {
    const int c = cands[ci];
    const size_t need = (size_t)c * SQ * 1536 * 2        // qhi chunk
                      + M * 512 * 2                      // avhi
                      + 1536 * 512 * 2 + 512 * 512 * 2   // Wqb + Wob
                      + (size_t)BB * DM * 4 + (size_t)BB * DM * 2;  // slack + rhkb
    if (need <= ws_size) { CB = c; break; }
  }

  char* p = (char*)d_ws;
  unsigned short* qhi  = (unsigned short*)p; p += (size_t)CB * SQ * 1536 * 2;
  unsigned short* avhi = (unsigned short*)p; p += M * 512 * 2;
  unsigned short* Wqb  = (unsigned short*)p; p += (size_t)1536 * 512 * 2;
  unsigned short* Wob  = (unsigned short*)p; p += (size_t)512 * 512 * 2;
  unsigned short* rhkb = (unsigned short*)p;

  // LN (9216 blocks, 4 rows each) + weight-conv tail (1024 blocks)
  ln2_kernel<<<(SQ * BB) / 4 + 1024, 256, 0, stream>>>(
      inp, ln1_g, ln1_b, ln2_g, ln2_b, hbhi, Wqkv, Wo, Wqb, Wob);
  rhk_kernel<<<dim3(BB, DM / 256), 256, 0, stream>>>(inp, Wr, rhkb);

  for (int b0 = 0; b0 < BB; b0 += CB) {
    const int Mc = CB * SQ;
    // QKV: hi-only (K=512) — outputs get bf16-rounded anyway.
    gemm_mfma<<<dim3(1536 / 128, Mc / 128), 256, 0, stream>>>(
        hbhi + (size_t)b0 * SQ * DM, hbhi + (size_t)b0 * SQ * DM, Wqb,
        qhi, nullptr, 1536, 0, 8);
    attn_mfma<<<CB * NH, 768, 0, stream>>>(qhi, rhkb, rwb, rrb, avhi, b0);
  }

  // OUT: hi-only (K=512) — av-lo plane dropped (R15); error model predicts
  // +1-2 bf16 quanta on absmax, within threshold.
  gemm_mfma<<<dim3(512 / 128, M / 128), 256, 0, stream>>>(
      avhi, avhi, Wob, nullptr, out, 512, 1, 8);
}